// Round 2
// baseline (270.308 us; speedup 1.0000x reference)
//
#include <hip/hip_runtime.h>
#include <stdint.h>

#define B_   8
#define N_   2048
#define C_   128
#define EPS_ 0.1f

typedef __attribute__((ext_vector_type(8))) short short8;
typedef __attribute__((ext_vector_type(4))) float f32x4;

__device__ __forceinline__ unsigned short f2bf(float f) {
    union { float f; uint32_t u; } v; v.f = f;
    uint32_t u = v.u + 0x7FFF + ((v.u >> 16) & 1);   // RNE (inputs are finite)
    return (unsigned short)(u >> 16);
}

// ---------------- kernel 0: Wt[o][k] = bf16(W[k][o]) ----------------
__global__ __launch_bounds__(128) void k_wt(const float* __restrict__ W,
                                            unsigned short* __restrict__ Wt) {
    const int o = blockIdx.x, k = threadIdx.x;
    Wt[o * C_ + k] = f2bf(W[k * C_ + o]);
}

// ---- kernel 1: ht[b][o][j]=bf16(h), al/ar = h . w_att (MFMA x@W) ----
__global__ __launch_bounds__(256) void k_h(
    const float* __restrict__ x, const unsigned short* __restrict__ Wt,
    const float* __restrict__ wl, const float* __restrict__ wr,
    unsigned short* __restrict__ ht, float* __restrict__ al, float* __restrict__ ar)
{
    const int b    = blockIdx.x >> 5;
    const int i0   = (blockIdx.x & 31) * 64;
    const int t    = threadIdx.x;
    const int lane = t & 63;
    const int wid  = t >> 6;

    // [row][k] bf16, XOR-swizzled in 16B units: u' = u ^ (row&15)
    __shared__ __align__(16) unsigned short xs[64 * 128];
    __shared__ __align__(16) unsigned short ws[128 * 128];

    // stage x (fp32 -> bf16)
    #pragma unroll
    for (int p = 0; p < 4; ++p) {
        const int s = p * 256 + t, row = s >> 4, u = s & 15;
        const float* gp = x + ((size_t)(b * N_ + i0 + row) * C_ + u * 8);
        float4 f0 = *(const float4*)gp;
        float4 f1 = *(const float4*)(gp + 4);
        short8 tv;
        tv[0] = (short)f2bf(f0.x); tv[1] = (short)f2bf(f0.y);
        tv[2] = (short)f2bf(f0.z); tv[3] = (short)f2bf(f0.w);
        tv[4] = (short)f2bf(f1.x); tv[5] = (short)f2bf(f1.y);
        tv[6] = (short)f2bf(f1.z); tv[7] = (short)f2bf(f1.w);
        *(short8*)&xs[row * 128 + (u ^ (row & 15)) * 8] = tv;
    }
    // stage Wt (already bf16)
    #pragma unroll
    for (int p = 0; p < 8; ++p) {
        const int s = p * 256 + t, o = s >> 4, u = s & 15;
        int4 v = *(const int4*)(Wt + o * C_ + u * 8);
        *(int4*)&ws[o * 128 + (u ^ (o & 15)) * 8] = v;
    }
    __syncthreads();

    const int m0 = wid * 16, lr = lane & 15, q = lane >> 4;
    f32x4 acc[8];
    #pragma unroll
    for (int i = 0; i < 8; ++i) acc[i] = (f32x4){0.f, 0.f, 0.f, 0.f};

    #pragma unroll
    for (int s = 0; s < 4; ++s) {
        const int m = m0 + lr;
        short8 af = *(const short8*)&xs[m * 128 + ((s * 4 + q) ^ (m & 15)) * 8];
        #pragma unroll
        for (int tt = 0; tt < 8; ++tt) {
            const int o = tt * 16 + lr;
            short8 bf = *(const short8*)&ws[o * 128 + ((s * 4 + q) ^ (o & 15)) * 8];
            acc[tt] = __builtin_amdgcn_mfma_f32_16x16x32_bf16(af, bf, acc[tt], 0, 0, 0);
        }
    }

    // epilogue: ht (transposed bf16) + al/ar partials
    float pl[4] = {0.f, 0.f, 0.f, 0.f}, pr[4] = {0.f, 0.f, 0.f, 0.f};
    const int j0 = i0 + m0 + q * 4;     // D rows = j index, 4 consecutive
    #pragma unroll
    for (int tt = 0; tt < 8; ++tt) {
        const int o = tt * 16 + lr;
        const float wlv = wl[o], wrv = wr[o];
        unsigned int lo = (unsigned int)f2bf(acc[tt][0]) | ((unsigned int)f2bf(acc[tt][1]) << 16);
        unsigned int hi = (unsigned int)f2bf(acc[tt][2]) | ((unsigned int)f2bf(acc[tt][3]) << 16);
        uint2 u2; u2.x = lo; u2.y = hi;
        *(uint2*)&ht[((size_t)(b * C_ + o)) * N_ + j0] = u2;
        #pragma unroll
        for (int r = 0; r < 4; ++r) {
            pl[r] = fmaf(acc[tt][r], wlv, pl[r]);
            pr[r] = fmaf(acc[tt][r], wrv, pr[r]);
        }
    }
    #pragma unroll
    for (int msk = 1; msk < 16; msk <<= 1) {
        #pragma unroll
        for (int r = 0; r < 4; ++r) {
            pl[r] += __shfl_xor(pl[r], msk, 64);
            pr[r] += __shfl_xor(pr[r], msk, 64);
        }
    }
    if (lr == 0) {
        #pragma unroll
        for (int r = 0; r < 4; ++r) {
            al[b * N_ + j0 + r] = pl[r];
            ar[b * N_ + j0 + r] = pr[r];
        }
    }
}

// ---- kernel 2: out = mask(tanh(ar_i*al_j)) @ h + eps*x0  (MFMA) ----
// 512 blocks x 256 thr; i-tile 32, per-wave output 16x64.
// ZERO LDS, ZERO barriers: A (alpha) is computed in registers directly in
// MFMA fragment layout from adj+al; B is loaded straight from ht (L2/L3
// resident, [o][j]-contiguous == B-fragment layout). Register
// double-buffered over K-chunks of 64.
struct Pref {                        // one K-chunk of operands (64 VGPRs)
    int4   a[4];                     // adj: [s2*2+half], 8 ints per k-step
    float4 l[4];                     // al:  [s2*2+half], 8 floats per k-step
    int4   hb[8];                    // ht B-frags: [s2*4+tt], 16B each
};

__global__ __launch_bounds__(256) void k_out(
    const int* __restrict__ adj, const unsigned short* __restrict__ ht,
    const float* __restrict__ al, const float* __restrict__ ar,
    const float* __restrict__ x0, float* __restrict__ out)
{
    const int b    = blockIdx.x >> 6;
    const int i0   = (blockIdx.x & 63) * 32;
    const int t    = threadIdx.x;
    const int lane = t & 63;
    const int wid  = t >> 6;

    const int m0 = (wid & 1) * 16, n0 = (wid >> 1) * 64;
    const int lr = lane & 15, q = lane >> 4;
    const int q8 = q * 8;

    // per-lane row/pointer setup
    const int irow = i0 + m0 + lr;                               // A row (i)
    const float arv = ar[b * N_ + irow];
    const float tl  = 2.f * arv;
    const int*            adjp = adj + ((size_t)(b * N_) + irow) * N_;
    const float*          alp  = al + b * N_;
    const unsigned short* hbp  = ht + ((size_t)(b * C_) + n0 + lr) * N_;

    auto ldc = [&](int c) -> Pref {
        Pref P;
        const int j0 = c * 64 + q8;
        #pragma unroll
        for (int s2 = 0; s2 < 2; ++s2) {
            P.a[s2 * 2]     = *(const int4*)(adjp + j0 + s2 * 32);
            P.a[s2 * 2 + 1] = *(const int4*)(adjp + j0 + s2 * 32 + 4);
            P.l[s2 * 2]     = *(const float4*)(alp + j0 + s2 * 32);
            P.l[s2 * 2 + 1] = *(const float4*)(alp + j0 + s2 * 32 + 4);
            #pragma unroll
            for (int tt = 0; tt < 4; ++tt)
                P.hb[s2 * 4 + tt] =
                    *(const int4*)(hbp + (size_t)(tt * 16) * N_ + j0 + s2 * 32);
        }
        return P;
    };

    f32x4 acc[4];
    #pragma unroll
    for (int i = 0; i < 4; ++i) acc[i] = (f32x4){0.f, 0.f, 0.f, 0.f};

    auto cmp = [&](const Pref& P) {
        #pragma unroll
        for (int s2 = 0; s2 < 2; ++s2) {
            const int*   av = (const int*)&P.a[s2 * 2];
            const float* lv = (const float*)&P.l[s2 * 2];
            short8 af;
            #pragma unroll
            for (int e = 0; e < 8; ++e) {
                float ex = __expf(tl * lv[e]);
                float th = 1.f - 2.f / (ex + 1.f);
                af[e] = av[e] ? (short)f2bf(th) : (short)0;
            }
            #pragma unroll
            for (int tt = 0; tt < 4; ++tt) {
                short8 bf = *(const short8*)&P.hb[s2 * 4 + tt];
                acc[tt] = __builtin_amdgcn_mfma_f32_16x16x32_bf16(af, bf, acc[tt], 0, 0, 0);
            }
        }
    };

    // register double-buffer over 32 chunks; loads of the next chunk are
    // issued before the waitcnt on the current chunk's data.
    Pref PA = ldc(0);
    #pragma unroll 1
    for (int c = 0; c < 32; c += 2) {
        Pref PB = ldc(c + 1);
        cmp(PA);
        if (c + 2 < 32) PA = ldc(c + 2);
        cmp(PB);
    }

    // ---- epilogue: out = acc + eps*x0 ----
    #pragma unroll
    for (int tt = 0; tt < 4; ++tt) {
        const int o = n0 + tt * 16 + lr;
        #pragma unroll
        for (int r = 0; r < 4; ++r) {
            const int row = i0 + m0 + q * 4 + r;
            const size_t idx = ((size_t)(b * N_) + row) * C_ + o;
            out[idx] = acc[tt][r] + EPS_ * x0[idx];
        }
    }
}

extern "C" void kernel_launch(void* const* d_in, const int* in_sizes, int n_in,
                              void* d_out, int out_size, void* d_ws, size_t ws_size,
                              hipStream_t stream) {
    const float* x   = (const float*)d_in[0];
    const float* x0  = (const float*)d_in[1];
    const int*   adj = (const int*)d_in[2];
    const float* W   = (const float*)d_in[3];
    const float* wl  = (const float*)d_in[4];
    const float* wr  = (const float*)d_in[5];
    float* out = (float*)d_out;

    unsigned short* ht = (unsigned short*)d_ws;                      // 4 MB
    float* al = (float*)((char*)d_ws + (size_t)B_ * C_ * N_ * 2);
    float* ar = al + B_ * N_;
    unsigned short* Wt = (unsigned short*)(ar + B_ * N_);            // 32 KB

    k_wt <<<C_,             C_,  0, stream>>>(W, Wt);
    k_h  <<<B_ * (N_ / 64), 256, 0, stream>>>(x, Wt, wl, wr, ht, al, ar);
    k_out<<<B_ * (N_ / 32), 256, 0, stream>>>(adj, ht, al, ar, x0, out);
}

// Round 3
// 240.564 us; speedup vs baseline: 1.1236x; 1.1236x over previous
//
#include <hip/hip_runtime.h>
#include <stdint.h>

#define B_   8
#define N_   2048
#define C_   128
#define EPS_ 0.1f

typedef __attribute__((ext_vector_type(8))) short short8;
typedef __attribute__((ext_vector_type(4))) float f32x4;

__device__ __forceinline__ unsigned short f2bf(float f) {
    union { float f; uint32_t u; } v; v.f = f;
    uint32_t u = v.u + 0x7FFF + ((v.u >> 16) & 1);   // RNE (inputs are finite)
    return (unsigned short)(u >> 16);
}

// ---------------- kernel 0: Wt[o][k] = bf16(W[k][o]) ----------------
__global__ __launch_bounds__(128) void k_wt(const float* __restrict__ W,
                                            unsigned short* __restrict__ Wt) {
    const int o = blockIdx.x, k = threadIdx.x;
    Wt[o * C_ + k] = f2bf(W[k * C_ + o]);
}

// ---- kernel 1: ht[b][o][j]=bf16(h), al/ar = h . w_att (MFMA x@W) ----
__global__ __launch_bounds__(256) void k_h(
    const float* __restrict__ x, const unsigned short* __restrict__ Wt,
    const float* __restrict__ wl, const float* __restrict__ wr,
    unsigned short* __restrict__ ht, float* __restrict__ al, float* __restrict__ ar)
{
    const int b    = blockIdx.x >> 5;
    const int i0   = (blockIdx.x & 31) * 64;
    const int t    = threadIdx.x;
    const int lane = t & 63;
    const int wid  = t >> 6;

    // [row][k] bf16, XOR-swizzled in 16B units: u' = u ^ (row&15)
    __shared__ __align__(16) unsigned short xs[64 * 128];
    __shared__ __align__(16) unsigned short ws[128 * 128];

    // stage x (fp32 -> bf16)
    #pragma unroll
    for (int p = 0; p < 4; ++p) {
        const int s = p * 256 + t, row = s >> 4, u = s & 15;
        const float* gp = x + ((size_t)(b * N_ + i0 + row) * C_ + u * 8);
        float4 f0 = *(const float4*)gp;
        float4 f1 = *(const float4*)(gp + 4);
        short8 tv;
        tv[0] = (short)f2bf(f0.x); tv[1] = (short)f2bf(f0.y);
        tv[2] = (short)f2bf(f0.z); tv[3] = (short)f2bf(f0.w);
        tv[4] = (short)f2bf(f1.x); tv[5] = (short)f2bf(f1.y);
        tv[6] = (short)f2bf(f1.z); tv[7] = (short)f2bf(f1.w);
        *(short8*)&xs[row * 128 + (u ^ (row & 15)) * 8] = tv;
    }
    // stage Wt (already bf16)
    #pragma unroll
    for (int p = 0; p < 8; ++p) {
        const int s = p * 256 + t, o = s >> 4, u = s & 15;
        int4 v = *(const int4*)(Wt + o * C_ + u * 8);
        *(int4*)&ws[o * 128 + (u ^ (o & 15)) * 8] = v;
    }
    __syncthreads();

    const int m0 = wid * 16, lr = lane & 15, q = lane >> 4;
    f32x4 acc[8];
    #pragma unroll
    for (int i = 0; i < 8; ++i) acc[i] = (f32x4){0.f, 0.f, 0.f, 0.f};

    #pragma unroll
    for (int s = 0; s < 4; ++s) {
        const int m = m0 + lr;
        short8 af = *(const short8*)&xs[m * 128 + ((s * 4 + q) ^ (m & 15)) * 8];
        #pragma unroll
        for (int tt = 0; tt < 8; ++tt) {
            const int o = tt * 16 + lr;
            short8 bf = *(const short8*)&ws[o * 128 + ((s * 4 + q) ^ (o & 15)) * 8];
            acc[tt] = __builtin_amdgcn_mfma_f32_16x16x32_bf16(af, bf, acc[tt], 0, 0, 0);
        }
    }

    // epilogue: ht (transposed bf16) + al/ar partials
    float pl[4] = {0.f, 0.f, 0.f, 0.f}, pr[4] = {0.f, 0.f, 0.f, 0.f};
    const int j0 = i0 + m0 + q * 4;     // D rows = j index, 4 consecutive
    #pragma unroll
    for (int tt = 0; tt < 8; ++tt) {
        const int o = tt * 16 + lr;
        const float wlv = wl[o], wrv = wr[o];
        unsigned int lo = (unsigned int)f2bf(acc[tt][0]) | ((unsigned int)f2bf(acc[tt][1]) << 16);
        unsigned int hi = (unsigned int)f2bf(acc[tt][2]) | ((unsigned int)f2bf(acc[tt][3]) << 16);
        uint2 u2; u2.x = lo; u2.y = hi;
        *(uint2*)&ht[((size_t)(b * C_ + o)) * N_ + j0] = u2;
        #pragma unroll
        for (int r = 0; r < 4; ++r) {
            pl[r] = fmaf(acc[tt][r], wlv, pl[r]);
            pr[r] = fmaf(acc[tt][r], wrv, pr[r]);
        }
    }
    #pragma unroll
    for (int msk = 1; msk < 16; msk <<= 1) {
        #pragma unroll
        for (int r = 0; r < 4; ++r) {
            pl[r] += __shfl_xor(pl[r], msk, 64);
            pr[r] += __shfl_xor(pr[r], msk, 64);
        }
    }
    if (lr == 0) {
        #pragma unroll
        for (int r = 0; r < 4; ++r) {
            al[b * N_ + j0 + r] = pl[r];
            ar[b * N_ + j0 + r] = pr[r];
        }
    }
}

// ---- kernel 2: out = mask(tanh(ar_i*al_j)) @ h + eps*x0  (MFMA) ----
// Hybrid: A (alpha) staged through a tiny LDS buffer (coalesced adj reads,
// tanh computed once per element, LDS transpose to fragment layout);
// B (ht) loaded DIRECTLY from global into registers (L2-resident,
// [o][j]-contiguous == 16B/lane fragment). 512 blocks x 256 thr;
// double-buffered a_s (4 KB/chunk) + double-buffered HB regs; 1 barrier/chunk.
struct SD {                          // stage-side data for one chunk (16 VGPR)
    int4   a0, a1;                   // adj[irow][j0 + jq*8 + 0..7]
    float4 l0, l1;                   // al  [j0 + jq*8 + 0..7]
};
struct HB {                          // B fragments for one chunk (32 VGPR)
    int4 h[8];                       // [s2*4 + tt]
};

__global__ __launch_bounds__(256, 2) void k_out(
    const int* __restrict__ adj, const unsigned short* __restrict__ ht,
    const float* __restrict__ al, const float* __restrict__ ar,
    const float* __restrict__ x0, float* __restrict__ out)
{
    const int b    = blockIdx.x >> 6;
    const int i0   = (blockIdx.x & 63) * 32;
    const int t    = threadIdx.x;
    const int lane = t & 63;
    const int wid  = t >> 6;

    // alpha tile only: [32 rows][64 j] bf16, double-buffered, XOR-swizzled
    __shared__ __align__(16) unsigned short a_s[2][32 * 64];    // 8 KB

    // ---- stage-side indexing (coalesced over adj rows) ----
    const int arow = t >> 3;            // 0..31
    const int jq   = t & 7;             // 8-j unit within chunk
    const float arv = ar[b * N_ + i0 + arow];
    const float tl  = 2.f * arv;
    const int*   adjp = adj + ((size_t)(b * N_) + i0 + arow) * N_ + jq * 8;
    const float* alp  = al + b * N_ + jq * 8;

    auto ld_sd = [&](int c) -> SD {
        SD P;
        const int j0 = c * 64;
        P.a0 = *(const int4*)(adjp + j0);
        P.a1 = *(const int4*)(adjp + j0 + 4);
        P.l0 = *(const float4*)(alp + j0);
        P.l1 = *(const float4*)(alp + j0 + 4);
        return P;
    };

    auto stage = [&](int buf, const SD& P) {
        short8 pk;
        const int*   av = (const int*)&P.a0;
        const float* lv = (const float*)&P.l0;
        #pragma unroll
        for (int e = 0; e < 8; ++e) {
            float ex = __expf(tl * lv[e]);
            float th = 1.f - 2.f * __builtin_amdgcn_rcpf(ex + 1.f);
            pk[e] = av[e] ? (short)f2bf(th) : (short)0;
        }
        const int su = (jq ^ (arow & 7)) * 8;
        *(short8*)&a_s[buf][arow * 64 + su] = pk;
    };

    // ---- mma-side indexing ----
    const int m0 = (wid & 1) * 16, n0 = (wid >> 1) * 64;
    const int lr = lane & 15, q = lane >> 4;
    const unsigned short* hbp = ht + ((size_t)(b * C_) + n0 + lr) * N_ + q * 8;

    auto ld_hb = [&](int c) -> HB {
        HB H;
        const int j0 = c * 64;
        #pragma unroll
        for (int s2 = 0; s2 < 2; ++s2)
            #pragma unroll
            for (int tt = 0; tt < 4; ++tt)
                H.h[s2 * 4 + tt] =
                    *(const int4*)(hbp + (size_t)(tt * 16) * N_ + j0 + s2 * 32);
        return H;
    };

    f32x4 acc[4];
    #pragma unroll
    for (int i = 0; i < 4; ++i) acc[i] = (f32x4){0.f, 0.f, 0.f, 0.f};

    auto mma = [&](int buf, const HB& H) {
        #pragma unroll
        for (int s2 = 0; s2 < 2; ++s2) {
            const int m = m0 + lr;
            short8 afr = *(const short8*)&a_s[buf][m * 64 + ((s2 * 4 + q) ^ (m & 7)) * 8];
            #pragma unroll
            for (int tt = 0; tt < 4; ++tt) {
                short8 bfr = *(const short8*)&H.h[s2 * 4 + tt];
                acc[tt] = __builtin_amdgcn_mfma_f32_16x16x32_bf16(afr, bfr, acc[tt], 0, 0, 0);
            }
        }
    };

    // ---- prologue: issue all prefetches, stage chunk 0 ----
    SD sd0 = ld_sd(0);
    SD sdA = ld_sd(1);
    SD sdB = ld_sd(2);
    HB hb0 = ld_hb(0);
    HB hb1 = ld_hb(1);
    stage(0, sd0);
    __syncthreads();

    // Invariant at top of iter cc: a_s[0] = chunk 2cc; sdA = 2cc+1, sdB = 2cc+2;
    // hb0 = 2cc, hb1 = 2cc+1.
    for (int cc = 0; cc < 16; ++cc) {
        stage(1, sdA);                      // a_s[1] <- chunk 2cc+1
        if (cc < 15) sdA = ld_sd(2 * cc + 3);
        mma(0, hb0);                        // chunk 2cc
        if (cc < 15) hb0 = ld_hb(2 * cc + 2);
        __syncthreads();

        if (cc < 15) {
            stage(0, sdB);                  // a_s[0] <- chunk 2cc+2
            if (cc < 14) sdB = ld_sd(2 * cc + 4);
        }
        mma(1, hb1);                        // chunk 2cc+1
        if (cc < 15) hb1 = ld_hb(2 * cc + 3);
        __syncthreads();
    }

    // ---- epilogue: out = acc + eps*x0 ----
    #pragma unroll
    for (int tt = 0; tt < 4; ++tt) {
        const int o = n0 + tt * 16 + lr;
        #pragma unroll
        for (int r = 0; r < 4; ++r) {
            const int row = i0 + m0 + q * 4 + r;
            const size_t idx = ((size_t)(b * N_) + row) * C_ + o;
            out[idx] = acc[tt][r] + EPS_ * x0[idx];
        }
    }
}

extern "C" void kernel_launch(void* const* d_in, const int* in_sizes, int n_in,
                              void* d_out, int out_size, void* d_ws, size_t ws_size,
                              hipStream_t stream) {
    const float* x   = (const float*)d_in[0];
    const float* x0  = (const float*)d_in[1];
    const int*   adj = (const int*)d_in[2];
    const float* W   = (const float*)d_in[3];
    const float* wl  = (const float*)d_in[4];
    const float* wr  = (const float*)d_in[5];
    float* out = (float*)d_out;

    unsigned short* ht = (unsigned short*)d_ws;                      // 4 MB
    float* al = (float*)((char*)d_ws + (size_t)B_ * C_ * N_ * 2);
    float* ar = al + B_ * N_;
    unsigned short* Wt = (unsigned short*)(ar + B_ * N_);            // 32 KB

    k_wt <<<C_,             C_,  0, stream>>>(W, Wt);
    k_h  <<<B_ * (N_ / 64), 256, 0, stream>>>(x, Wt, wl, wr, ht, al, ar);
    k_out<<<B_ * (N_ / 32), 256, 0, stream>>>(adj, ht, al, ar, x0, out);
}